// Round 3
// baseline (44.909 us; speedup 1.0000x reference)
//
#include <hip/hip_runtime.h>

// NodeSepDropoutLayer: ROWS=65536, COLS=512, P=0.6, PNT=0.5, NSP=0.9, NCLASS=10
//
// Constant-folded reference (R0 analysis): split == cols-split == 256 so
// nz_final = 16777216 < ntz = 20132659 -> `reached` always False, every row
// "can", remaining_p = 3355443/2^24 exactly (f32-exact).
//
// Per row r:
//   take_t = (labels[r] in target_classes) && start_attack && (row_rand[r] <= 0.9f)
//   keep cols = take_t ? [256,512) : [0,256)
//   out = keep && (residual_rand > remaining_p) ? input * 2.5f : 0
//
// R2 -> R3: grid-stride, 2048 long-lived blocks, 16 float4/thread fully
// unrolled (deep ILP: many outstanding loads/thread instead of 1), and
// readfirstlane-scalarized labels/row_rand loads (row is wave-uniform: a
// 64-lane wave covers exactly half a row of 128 float4s). nt stores kept
// (R2: +25% — write stream bypasses caches, preserving L3 for the read set).

#define NSD_ROWS 65536
#define NSD_COLS 512
#define NSD_TOTAL_F4 (NSD_ROWS * (NSD_COLS / 4))   // 8388608
#define NSD_BLOCKS 2048
#define NSD_THREADS 256
#define NSD_ITERS (NSD_TOTAL_F4 / (NSD_BLOCKS * NSD_THREADS))  // 16

typedef float f32x4 __attribute__((ext_vector_type(4)));

__global__ __launch_bounds__(NSD_THREADS) void NodeSepDropoutLayer_72164040508019_kernel(
    const float* __restrict__ input,
    const int*   __restrict__ labels,
    const int*   __restrict__ tclass,
    const int*   __restrict__ start_attack,
    const float* __restrict__ row_rand,
    const float* __restrict__ resid_rand,
    float*       __restrict__ out)
{
    const float remaining_p = 3355443.0f / 16777216.0f;  // exact f32

    const int tc0 = tclass[0];
    const int tc1 = tclass[1];
    const bool attack = (start_attack[0] != 0);

    const unsigned tid    = blockIdx.x * NSD_THREADS + threadIdx.x;
    const unsigned stride = NSD_BLOCKS * NSD_THREADS;   // 524288 f4 = 4096 rows

#pragma unroll
    for (int it = 0; it < NSD_ITERS; ++it) {
        const unsigned idx = tid + (unsigned)it * stride;
        const int row = (int)(idx >> 7);          // 128 f4/row; wave-uniform
        const int c   = (int)(idx & 127) * 4;

        // row is identical across the 64 lanes of a wave -> scalarize the
        // per-row loads (s_load via SGPR address instead of 64 vmem loads).
        const int urow = __builtin_amdgcn_readfirstlane(row);
        const int   lab = labels[urow];
        const float rrw = row_rand[urow];

        const bool is_t   = (lab == tc0) | (lab == tc1);
        const bool take_t = is_t & attack & (rrw <= 0.9f);
        const bool keep   = take_t ? (c >= 256) : (c < 256);

        const long long e = ((long long)row << 9) + c;

        f32x4 o = (f32x4)(0.0f);
        if (keep) {
            const f32x4 in = *(const f32x4*)(input + e);
            const f32x4 rr = *(const f32x4*)(resid_rand + e);
            o.x = (rr.x > remaining_p) ? in.x * 2.5f : 0.0f;
            o.y = (rr.y > remaining_p) ? in.y * 2.5f : 0.0f;
            o.z = (rr.z > remaining_p) ? in.z * 2.5f : 0.0f;
            o.w = (rr.w > remaining_p) ? in.w * 2.5f : 0.0f;
        }
        __builtin_nontemporal_store(o, (f32x4*)(out + e));
    }
}

extern "C" void kernel_launch(void* const* d_in, const int* in_sizes, int n_in,
                              void* d_out, int out_size, void* d_ws, size_t ws_size,
                              hipStream_t stream) {
    const float* input        = (const float*)d_in[0];
    const int*   labels       = (const int*)d_in[1];
    const int*   tclass       = (const int*)d_in[2];
    const int*   start_attack = (const int*)d_in[3];
    const float* row_rand     = (const float*)d_in[4];
    const float* resid_rand   = (const float*)d_in[5];
    float*       out          = (float*)d_out;

    NodeSepDropoutLayer_72164040508019_kernel<<<NSD_BLOCKS, NSD_THREADS, 0, stream>>>(
        input, labels, tclass, start_attack, row_rand, resid_rand, out);
}

// Round 4
// 40.866 us; speedup vs baseline: 1.0989x; 1.0989x over previous
//
#include <hip/hip_runtime.h>

// NodeSepDropoutLayer: ROWS=65536, COLS=512, P=0.6, PNT=0.5, NSP=0.9, NCLASS=10
//
// Constant-folded reference (R0 analysis): split == cols-split == 256 so
// nz_final = 16777216 < ntz = 20132659 -> `reached` always False, every row
// "can", remaining_p = 3355443/2^24 exactly (f32-exact).
//
// Per row r:
//   take_t = (labels[r] in target_classes) && start_attack && (row_rand[r] <= 0.9f)
//   keep cols = take_t ? [256,512) : [0,256)
//   out = keep && (residual_rand > remaining_p) ? input * 2.5f : 0
//
// History: R1 plain f4 = 53.2us. R2 +nt stores = 40.3us (write stream out of
// L2/L3 -> read set partially L3-resident). R3 grid-stride+readfirstlane =
// 44.9us REGRESSION (broke sequential DRAM stream; s_load waits serialized).
// R4: back to R2 structure; store via inline-asm global_store_dwordx4 with
// `nt sc0 sc1` — strongest per-inst stream/no-allocate policy — probing
// whether the 134MB/replay write stream can bypass the Infinity Cache so the
// 128.5MiB read set stays fully L3-resident across graph replays.

#define NSD_ROWS 65536
#define NSD_COLS 512

typedef float f32x4 __attribute__((ext_vector_type(4)));

__global__ __launch_bounds__(256) void NodeSepDropoutLayer_72164040508019_kernel(
    const float* __restrict__ input,
    const int*   __restrict__ labels,
    const int*   __restrict__ tclass,
    const int*   __restrict__ start_attack,
    const float* __restrict__ row_rand,
    const float* __restrict__ resid_rand,
    float*       __restrict__ out)
{
    const float remaining_p = 3355443.0f / 16777216.0f;  // exact f32

    const int tc0 = tclass[0];
    const int tc1 = tclass[1];
    const bool attack = (start_attack[0] != 0);

    // 1 float4/thread; 128 f4 per row -> each 64-lane wave covers exactly
    // half a row (wave-uniform keep/zero: no divergence, zero-half waves
    // issue no loads).
    const unsigned idx = blockIdx.x * blockDim.x + threadIdx.x;  // < 8388608
    const int row = (int)(idx >> 7);
    const int c   = (int)(idx & 127) * 4;

    const int lab = labels[row];
    const bool is_t   = (lab == tc0) | (lab == tc1);
    const bool take_t = is_t & attack & (row_rand[row] <= 0.9f);
    const bool keep   = take_t ? (c >= 256) : (c < 256);

    const long long e = ((long long)row << 9) + c;

    f32x4 o = (f32x4)(0.0f);
    if (keep) {
        const f32x4 in = *(const f32x4*)(input + e);
        const f32x4 rr = *(const f32x4*)(resid_rand + e);
        o.x = (rr.x > remaining_p) ? in.x * 2.5f : 0.0f;
        o.y = (rr.y > remaining_p) ? in.y * 2.5f : 0.0f;
        o.z = (rr.z > remaining_p) ? in.z * 2.5f : 0.0f;
        o.w = (rr.w > remaining_p) ? in.w * 2.5f : 0.0f;
    }

    // Stream store: non-temporal + sc0/sc1 scope bits (max no-allocate hint).
    const float* p = out + e;
    asm volatile("global_store_dwordx4 %0, %1, off nt sc0 sc1"
                 :: "v"(p), "v"(o) : "memory");
}

extern "C" void kernel_launch(void* const* d_in, const int* in_sizes, int n_in,
                              void* d_out, int out_size, void* d_ws, size_t ws_size,
                              hipStream_t stream) {
    const float* input        = (const float*)d_in[0];
    const int*   labels       = (const int*)d_in[1];
    const int*   tclass       = (const int*)d_in[2];
    const int*   start_attack = (const int*)d_in[3];
    const float* row_rand     = (const float*)d_in[4];
    const float* resid_rand   = (const float*)d_in[5];
    float*       out          = (float*)d_out;

    const int total_f4 = NSD_ROWS * (NSD_COLS / 4);   // 8388608
    const int block = 256;
    const int grid  = total_f4 / block;               // 32768

    NodeSepDropoutLayer_72164040508019_kernel<<<grid, block, 0, stream>>>(
        input, labels, tclass, start_attack, row_rand, resid_rand, out);
}